// Round 7
// baseline (125.365 us; speedup 1.0000x reference)
//
#include <hip/hip_runtime.h>
#include <math.h>

// Chamfer loss, two 16384x3 fp32 clouds. Two stream launches.
//
// Pass 1: per-(qchunk, DB-slice) block, partial mins of (||b||^2 - 2 a.b).
//   v_pk_fma_f32 processes 2 DB points/instr. Query coords are packed
//   {even_query, odd_query} per VGPR pair and broadcast via VOP3P op_sel
//   (lo->both or hi->both), so NO splat registers and NO per-iteration
//   v_movs (R6's failure: compiler rematerialized {x,x} splats, doubling
//   VALU back to the scalar floor — VGPR_Count 44 < the 48 needed proved
//   splats weren't resident). 2 VALU instr/pair -> floor 13.7us.
// Pass 2: 2048 blocks; block = 16 queries x 64 slices, 4 loads/thread
//   (one shot, latency-parallel — R6's 64-deep per-thread load loop at 128
//   blocks crawled at ~180GB/s), min tree, sqrt, one atomicAdd per block.

typedef float v2f __attribute__((ext_vector_type(2)));

#define BLOCK  256
#define QPT    8      // queries per thread (4 even/odd pairs)
#define SLICES 64     // pass-1 grid = 16 qchunks * 64 = 1024 blocks

// d = X * bcast(q.lo) + C   (both product halves use q's LOW float)
__device__ __forceinline__ v2f pk_fma_blo(v2f X, v2f q, v2f C) {
    v2f d;
    asm("v_pk_fma_f32 %0, %1, %2, %3 op_sel:[0,0,0] op_sel_hi:[1,0,1]"
        : "=v"(d) : "v"(X), "v"(q), "v"(C));
    return d;
}
// d = X * bcast(q.hi) + C   (both product halves use q's HIGH float)
__device__ __forceinline__ v2f pk_fma_bhi(v2f X, v2f q, v2f C) {
    v2f d;
    asm("v_pk_fma_f32 %0, %1, %2, %3 op_sel:[0,1,0] op_sel_hi:[1,1,1]"
        : "=v"(d) : "v"(X), "v"(q), "v"(C));
    return d;
}

__global__ __launch_bounds__(BLOCK) void chamfer_partial_min(
    const float* __restrict__ state_x, const float* __restrict__ target,
    float* __restrict__ mins, float* __restrict__ out, int N)
{
    const int tid = threadIdx.x;
    const int twoN = 2 * N;
    const int qchunk = blockIdx.x / SLICES;     // block-uniform
    const int s = blockIdx.x % SLICES;
    const int qbase = qchunk * (BLOCK * QPT);   // 2048-query chunk, 2048 | N

    if (blockIdx.x == 0 && tid == 0) out[0] = 0.0f;  // for pass-2 atomicAdd

    const float* qcloud;
    const float* db;
    int qoff;
    if (qbase < N) { qcloud = target;  db = state_x; qoff = qbase;     }
    else           { qcloud = state_x; db = target;  qoff = qbase - N; }

    // Query coords packed {even, odd} per pair: 12 pairs = 24 VGPRs, no splats.
    v2f qx[QPT / 2], qy[QPT / 2], qz[QPT / 2];
    float m[QPT];
    #pragma unroll
    for (int k = 0; k < QPT / 2; ++k) {
        const int j0 = qoff + (2 * k + 0) * BLOCK + tid;
        const int j1 = qoff + (2 * k + 1) * BLOCK + tid;
        qx[k] = (v2f){-2.0f * qcloud[3 * j0 + 0], -2.0f * qcloud[3 * j1 + 0]};
        qy[k] = (v2f){-2.0f * qcloud[3 * j0 + 1], -2.0f * qcloud[3 * j1 + 1]};
        qz[k] = (v2f){-2.0f * qcloud[3 * j0 + 2], -2.0f * qcloud[3 * j1 + 2]};
        m[2 * k] = 3.0e38f; m[2 * k + 1] = 3.0e38f;
    }

    // Stage whole slice: sliceN = 256 pts = 128 pairs; pair layout
    // {x0,x1,y0,y1} and {z0,z1,w0,w1} (w = ||b||^2).
    __shared__ float4 tile[2 * (16384 / SLICES / 2)];
    const int sliceN = N / SLICES;
    const int pairs = sliceN / 2;
    const int base0 = s * sliceN;

    for (int p = tid; p < pairs; p += BLOCK) {
        const int g = base0 + 2 * p;
        const float x0 = db[3 * g + 0], y0 = db[3 * g + 1], z0 = db[3 * g + 2];
        const float x1 = db[3 * g + 3], y1 = db[3 * g + 4], z1 = db[3 * g + 5];
        tile[2 * p + 0] = make_float4(x0, x1, y0, y1);
        tile[2 * p + 1] = make_float4(z0, z1,
                                      fmaf(x0, x0, fmaf(y0, y0, z0 * z0)),
                                      fmaf(x1, x1, fmaf(y1, y1, z1 * z1)));
    }
    __syncthreads();

    // Per pair-iteration (2 DB pts): 2 broadcast ds_read_b128 + 32 VALU
    // (24 pk_fma + 8 v_min3), zero movs.
    #pragma unroll 4
    for (int p = 0; p < pairs; ++p) {
        const float4 A = tile[2 * p + 0];   // x0 x1 y0 y1
        const float4 B = tile[2 * p + 1];   // z0 z1 w0 w1
        const v2f X = (v2f){A.x, A.y};
        const v2f Y = (v2f){A.z, A.w};
        const v2f Z = (v2f){B.x, B.y};
        const v2f W = (v2f){B.z, B.w};
        #pragma unroll
        for (int k = 0; k < QPT / 2; ++k) {
            v2f d0 = pk_fma_blo(X, qx[k], W);
            d0 = pk_fma_blo(Y, qy[k], d0);
            d0 = pk_fma_blo(Z, qz[k], d0);
            m[2 * k] = fminf(fminf(m[2 * k], d0.x), d0.y);       // v_min3
            v2f d1 = pk_fma_bhi(X, qx[k], W);
            d1 = pk_fma_bhi(Y, qy[k], d1);
            d1 = pk_fma_bhi(Z, qz[k], d1);
            m[2 * k + 1] = fminf(fminf(m[2 * k + 1], d1.x), d1.y);
        }
    }

    #pragma unroll
    for (int q = 0; q < QPT; ++q)
        mins[(size_t)s * twoN + qbase + q * BLOCK + tid] = m[q];
}

// 2048 blocks; block = 16 queries x 64 slices. Thread t: query qg+(t&15),
// slice group t>>4 -> 4 loads. Wave shuffle-min (lanes +16,+32), LDS across
// waves, sqrt + sum on wave 0, one atomicAdd.
__global__ __launch_bounds__(BLOCK) void chamfer_finish(
    const float* __restrict__ state_x, const float* __restrict__ target,
    const float* __restrict__ mins, float* __restrict__ out, int N)
{
    const int tid = threadIdx.x;
    const int twoN = 2 * N;
    const int qg = blockIdx.x * 16;
    const int q = qg + (tid & 15);
    const int sgrp = tid >> 4;              // 0..15; slices sgrp*4..sgrp*4+3

    float v0 = mins[(size_t)(sgrp * 4 + 0) * twoN + q];
    float v1 = mins[(size_t)(sgrp * 4 + 1) * twoN + q];
    float v2 = mins[(size_t)(sgrp * 4 + 2) * twoN + q];
    float v3 = mins[(size_t)(sgrp * 4 + 3) * twoN + q];
    float mv = fminf(fminf(v0, v1), fminf(v2, v3));

    // lanes {c, c+16, c+32, c+48} share a query within each wave
    mv = fminf(mv, __shfl_xor(mv, 16, 64));
    mv = fminf(mv, __shfl_xor(mv, 32, 64));

    __shared__ float wmin[4][16];
    if ((tid & 63) < 16) wmin[tid >> 6][tid & 15] = mv;
    __syncthreads();

    if (tid < 16) {
        const float mm = fminf(fminf(wmin[0][tid], wmin[1][tid]),
                               fminf(wmin[2][tid], wmin[3][tid]));
        const int qi = qg + tid;
        const float* qc = (qi < N) ? target : state_x;
        const int qx2 = (qi < N) ? qi : qi - N;
        const float ax = qc[3 * qx2 + 0];
        const float ay = qc[3 * qx2 + 1];
        const float az = qc[3 * qx2 + 2];
        const float a2 = fmaf(ax, ax, fmaf(ay, ay, az * az));
        float v = sqrtf(fmaxf(a2 + mm, 0.0f));
        // sum 16 lanes
        for (int off = 8; off > 0; off >>= 1) v += __shfl_down(v, off, 64);
        if (tid == 0) atomicAdd(out, v * 5.0f / (float)N);
    }
}

extern "C" void kernel_launch(void* const* d_in, const int* in_sizes, int n_in,
                              void* d_out, int out_size, void* d_ws, size_t ws_size,
                              hipStream_t stream)
{
    const float* state_x = (const float*)d_in[0];
    const float* target  = (const float*)d_in[1];
    float* out = (float*)d_out;

    const int N = in_sizes[0] / 3;               // 16384
    const int twoN = 2 * N;
    float* mins = (float*)d_ws;                  // SLICES*2N floats = 8.4 MB

    const int qchunks = twoN / (BLOCK * QPT);    // 16
    chamfer_partial_min<<<qchunks * SLICES, BLOCK, 0, stream>>>(
        state_x, target, mins, out, N);
    chamfer_finish<<<twoN / 16, BLOCK, 0, stream>>>(
        state_x, target, mins, out, N);
}